// Round 3
// baseline (336.558 us; speedup 1.0000x reference)
//
#include <hip/hip_runtime.h>
#include <stdint.h>

#define HD   1024
#define LD   4096
#define BATCH 4
#define KLEN 8192           // 2*L
#define LAM  0.1f
#define TAP_CAP 65536

typedef __attribute__((ext_vector_type(8))) short short8x;
typedef __attribute__((ext_vector_type(4))) float float4x;

struct Tap { int hd; float v; };

__device__ inline unsigned short f2bf(float x) {
    union { float f; uint32_t u; } v; v.f = x;
    uint32_t u = v.u;
    u += 0x7fffu + ((u >> 16) & 1u);
    return (unsigned short)(u >> 16);
}

__device__ inline float silu_f(float x) { return x / (1.0f + __expf(-x)); }

// ---------------- fused: W fp32->bf16 (blocks 0..1023) + kernel scan --------
__global__ void k_prep(const float* __restrict__ kern, int* __restrict__ ntaps,
                       Tap* __restrict__ taps,
                       const float* __restrict__ W, unsigned short* __restrict__ Wbf) {
    if (blockIdx.x < 1024) {
        int i = blockIdx.x * 256 + threadIdx.x;
        const float4* w4 = (const float4*)W;
        float4 a = w4[i * 2], b = w4[i * 2 + 1];
        short8x o;
        o[0] = (short)f2bf(a.x); o[1] = (short)f2bf(a.y);
        o[2] = (short)f2bf(a.z); o[3] = (short)f2bf(a.w);
        o[4] = (short)f2bf(b.x); o[5] = (short)f2bf(b.y);
        o[6] = (short)f2bf(b.z); o[7] = (short)f2bf(b.w);
        *(short8x*)(Wbf + (int64_t)i * 8) = o;
        return;
    }
    int bid = blockIdx.x - 1024;
    const float4* k4 = (const float4*)kern;
    int64_t total4 = (int64_t)HD * KLEN / 4;
    int64_t stride = (int64_t)2048 * 256;
    for (int64_t i = (int64_t)bid * 256 + threadIdx.x; i < total4; i += stride) {
        float4 v = k4[i];
        float vals[4] = {v.x, v.y, v.z, v.w};
#pragma unroll
        for (int j = 0; j < 4; j++) {
            float a = fabsf(vals[j]) - LAM;
            if (a > 0.0f) {
                int e = (int)(i * 4 + j);
                int slot = atomicAdd(ntaps, 1);
                if (slot < TAP_CAP) { taps[slot].hd = e; taps[slot].v = copysignf(a, vals[j]); }
            }
        }
    }
}

// ---------------- general sparse conv (no-op when ntaps==0) -----------------
__global__ void k_conv(const float* __restrict__ u, const float* __restrict__ Dv,
                       const int* __restrict__ ntaps_p, const Tap* __restrict__ taps,
                       float* __restrict__ yfull) {
    int nt = *ntaps_p;
    if (nt == 0) return;
    nt = min(nt, TAP_CAP);
    int64_t total = (int64_t)BATCH * HD * LD;
    int64_t stride = (int64_t)gridDim.x * blockDim.x;
    for (int64_t i = (int64_t)blockIdx.x * blockDim.x + threadIdx.x; i < total; i += stride) {
        int t = (int)(i & (LD - 1));
        int64_t bh = i >> 12;
        int h = (int)(bh & (HD - 1));
        float acc = u[i] * Dv[h];
        for (int j = 0; j < nt; j++) {
            int hd = taps[j].hd;
            if ((hd >> 13) != h) continue;
            int d = hd & (KLEN - 1);
            int s;
            if (d <= t) s = t - d;
            else { s = t - d + KLEN; if (s >= LD) continue; }
            acc += taps[j].v * u[(bh << 12) + s];
        }
        yfull[i] = acc;
    }
}

// ---------------- V^T build: silu(u*D [+conv]) transposed to (B*L, H) bf16 --
__global__ __launch_bounds__(256) void k_vt(const float* __restrict__ u,
                                            const float* __restrict__ Dv,
                                            const float* __restrict__ yfull,
                                            const int* __restrict__ ntaps_p,
                                            unsigned short* __restrict__ Vt) {
    __shared__ float T[64 * 65];                 // index h*65 + l
    int nt = *ntaps_p;
    int lt = blockIdx.x * 64;
    int ht = blockIdx.y * 64;
    int b  = blockIdx.z;
    int tid = threadIdx.x;
    int lq = tid & 15;
    int hh = tid >> 4;
#pragma unroll
    for (int r = 0; r < 4; r++) {
        int h = hh + r * 16;
        int hg = ht + h;
        int64_t base = ((int64_t)b * HD + hg) * LD + lt + lq * 4;
        float4 v;
        if (nt == 0) {
            v = *(const float4*)(u + base);
            float d = Dv[hg];
            v.x *= d; v.y *= d; v.z *= d; v.w *= d;
        } else {
            v = *(const float4*)(yfull + base);
        }
        int p = h * 65 + lq * 4;
        T[p]     = silu_f(v.x);
        T[p + 1] = silu_f(v.y);
        T[p + 2] = silu_f(v.z);
        T[p + 3] = silu_f(v.w);
    }
    __syncthreads();
    int h8 = (tid & 7) * 8;
    int nb = tid >> 3;
#pragma unroll
    for (int p = 0; p < 2; p++) {
        int nl = nb + p * 32;
        short8x o;
#pragma unroll
        for (int j = 0; j < 8; j++) o[j] = (short)f2bf(T[(h8 + j) * 65 + nl]);
        int64_t n = (int64_t)b * LD + lt + nl;
        *(short8x*)(Vt + n * HD + ht + h8) = o;
    }
}

// ---------------- flatmm GEMM + GLU epilogue (NO LDS, no barriers) ----------
// Z = Wbf(2048x1024) * Vt^T(1024x16384); out[b,h,l] = (z_a+b_a)*sigmoid(z_g+b_g)
// Both MFMA operand fragments are 16 contiguous bytes/lane in memory, so each
// fragment is ONE global_load_dwordx4 (16 dense 64B lines/wave). K-loop fully
// unrolled: all 32 k-steps use 13-bit immediate offsets (<=1984B) off 12 base
// pointers -> zero per-step address math, compiler free to hoist loads.
__global__ __launch_bounds__(256, 2) void k_gemm(const unsigned short* __restrict__ Wbf,
                                                 const unsigned short* __restrict__ Vt,
                                                 const float* __restrict__ bvec,
                                                 float* __restrict__ out) {
    int mgrp = blockIdx.x & 7;       // m fast-varying (empirically best mapping)
    int ngrp = blockIdx.x >> 3;
    int m0 = mgrp * 128;
    int n0 = ngrp * 128;
    int tid = threadIdx.x;
    int lane = tid & 63;
    int wid  = tid >> 6;
    int wm = wid >> 1, wn = wid & 1;
    int l15 = lane & 15, quad = lane >> 4;

    const short8x* pa[4];
    const short8x* pg[4];
    const short8x* pb[4];
#pragma unroll
    for (int i = 0; i < 4; i++) {
        int ra = m0 + wm * 64 + i * 16 + l15;
        pa[i] = (const short8x*)(Wbf + (uint32_t)ra * 1024u + quad * 8);
        pg[i] = (const short8x*)(Wbf + (uint32_t)(ra + 1024) * 1024u + quad * 8);
        int nb = n0 + wn * 64 + i * 16 + l15;
        pb[i] = (const short8x*)(Vt + (uint32_t)nb * 1024u + quad * 8);
    }

    float4x acca[4][4], accg[4][4];
#pragma unroll
    for (int i = 0; i < 4; i++)
#pragma unroll
        for (int j = 0; j < 4; j++) {
            acca[i][j] = (float4x){0.f, 0.f, 0.f, 0.f};
            accg[i][j] = (float4x){0.f, 0.f, 0.f, 0.f};
        }

#pragma unroll
    for (int kt = 0; kt < 32; kt++) {
        short8x af[4], gf[4], bf[4];
#pragma unroll
        for (int i = 0; i < 4; i++) {
            af[i] = pa[i][kt * 4];       // byte offset kt*64 -> imm
            gf[i] = pg[i][kt * 4];
            bf[i] = pb[i][kt * 4];
        }
#pragma unroll
        for (int i = 0; i < 4; i++)
#pragma unroll
            for (int j = 0; j < 4; j++) {
                acca[i][j] = __builtin_amdgcn_mfma_f32_16x16x32_bf16(af[i], bf[j], acca[i][j], 0, 0, 0);
                accg[i][j] = __builtin_amdgcn_mfma_f32_16x16x32_bf16(gf[i], bf[j], accg[i][j], 0, 0, 0);
            }
    }

    // epilogue: out[b,h,l] = (a + b_a) * sigmoid(g + b_g)
    int b = n0 >> 12;
#pragma unroll
    for (int i = 0; i < 4; i++) {
        int h = m0 + wm * 64 + i * 16 + quad * 4;
        float ba[4], bg[4];
#pragma unroll
        for (int r = 0; r < 4; r++) { ba[r] = bvec[h + r]; bg[r] = bvec[1024 + h + r]; }
#pragma unroll
        for (int j = 0; j < 4; j++) {
            int n = n0 + wn * 64 + j * 16 + l15;
            int l = n & (LD - 1);
            float* op = out + ((int64_t)b * HD + h) * LD + l;
#pragma unroll
            for (int r = 0; r < 4; r++) {
                float av = acca[i][j][r] + ba[r];
                float gv = accg[i][j][r] + bg[r];
                op[(int64_t)r * LD] = av / (1.0f + __expf(-gv));
            }
        }
    }
}

extern "C" void kernel_launch(void* const* d_in, const int* in_sizes, int n_in,
                              void* d_out, int out_size, void* d_ws, size_t ws_size,
                              hipStream_t stream) {
    const float* u    = (const float*)d_in[0];   // (4,1024,4096)
    const float* kern = (const float*)d_in[1];   // (1,1024,8192)
    const float* Dv   = (const float*)d_in[2];   // (1,1024)
    const float* W    = (const float*)d_in[3];   // (2048,1024)
    const float* bv   = (const float*)d_in[4];   // (2048,)
    float* out = (float*)d_out;                  // (4,1024,4096)

    char* ws = (char*)d_ws;
    int* ntaps = (int*)ws;                                   // [0,256)
    Tap* taps  = (Tap*)(ws + 256);                           // 512 KiB cap
    unsigned short* Wbf = (unsigned short*)(ws + (1 << 20)); // 4 MiB
    unsigned short* Vt  = (unsigned short*)(ws + (8 << 20)); // 32 MiB
    float* yfull = (float*)(ws + (48 << 20));                // only touched if taps exist

    hipMemsetAsync(ntaps, 0, 256, stream);
    hipLaunchKernelGGL(k_prep, dim3(3072),      dim3(256), 0, stream, kern, ntaps, taps, W, Wbf);
    hipLaunchKernelGGL(k_conv, dim3(512),       dim3(256), 0, stream, u, Dv, ntaps, taps, yfull);
    hipLaunchKernelGGL(k_vt,   dim3(64, 16, 4), dim3(256), 0, stream, u, Dv, yfull, ntaps, Vt);
    hipLaunchKernelGGL(k_gemm, dim3(1024),      dim3(256), 0, stream, Wbf, Vt, bv, out);
}

// Round 4
// 219.387 us; speedup vs baseline: 1.5341x; 1.5341x over previous
//
#include <hip/hip_runtime.h>
#include <stdint.h>

#define HD   1024
#define LD   4096
#define BATCH 4
#define KLEN 8192           // 2*L
#define LAM  0.1f
#define TAP_CAP 65536

typedef __attribute__((ext_vector_type(8))) short short8x;
typedef __attribute__((ext_vector_type(4))) float float4x;

struct Tap { int hd; float v; };

__device__ inline unsigned short f2bf(float x) {
    union { float f; uint32_t u; } v; v.f = x;
    uint32_t u = v.u;
    u += 0x7fffu + ((u >> 16) & 1u);
    return (unsigned short)(u >> 16);
}

__device__ inline void gload16(const void* g, void* l) {
    __builtin_amdgcn_global_load_lds(
        (const __attribute__((address_space(1))) void*)g,
        (__attribute__((address_space(3))) void*)l,
        16, 0, 0);
}

__device__ inline float silu_f(float x) { return x / (1.0f + __expf(-x)); }

// ---------------- fused: W fp32->bf16 (blocks 0..1023) + kernel scan --------
__global__ void k_prep(const float* __restrict__ kern, int* __restrict__ ntaps,
                       Tap* __restrict__ taps,
                       const float* __restrict__ W, unsigned short* __restrict__ Wbf) {
    if (blockIdx.x < 1024) {
        int i = blockIdx.x * 256 + threadIdx.x;
        const float4* w4 = (const float4*)W;
        float4 a = w4[i * 2], b = w4[i * 2 + 1];
        short8x o;
        o[0] = (short)f2bf(a.x); o[1] = (short)f2bf(a.y);
        o[2] = (short)f2bf(a.z); o[3] = (short)f2bf(a.w);
        o[4] = (short)f2bf(b.x); o[5] = (short)f2bf(b.y);
        o[6] = (short)f2bf(b.z); o[7] = (short)f2bf(b.w);
        *(short8x*)(Wbf + (int64_t)i * 8) = o;
        return;
    }
    int bid = blockIdx.x - 1024;
    const float4* k4 = (const float4*)kern;
    int64_t total4 = (int64_t)HD * KLEN / 4;
    int64_t stride = (int64_t)2048 * 256;
    for (int64_t i = (int64_t)bid * 256 + threadIdx.x; i < total4; i += stride) {
        float4 v = k4[i];
        float vals[4] = {v.x, v.y, v.z, v.w};
#pragma unroll
        for (int j = 0; j < 4; j++) {
            float a = fabsf(vals[j]) - LAM;
            if (a > 0.0f) {
                int e = (int)(i * 4 + j);
                int slot = atomicAdd(ntaps, 1);
                if (slot < TAP_CAP) { taps[slot].hd = e; taps[slot].v = copysignf(a, vals[j]); }
            }
        }
    }
}

// ---------------- V^T build: silu(u*D + sparse conv) -> (B*L, H) bf16 -------
// Generic sparse-conv path inlined (block-uniform branch; nt==0 on this data).
__global__ __launch_bounds__(256) void k_vt(const float* __restrict__ u,
                                            const float* __restrict__ Dv,
                                            const int* __restrict__ ntaps_p,
                                            const Tap* __restrict__ taps,
                                            unsigned short* __restrict__ Vt) {
    __shared__ float T[64 * 65];                 // index h*65 + l
    int nt = *ntaps_p;
    int lt = blockIdx.x * 64;
    int ht = blockIdx.y * 64;
    int b  = blockIdx.z;
    int tid = threadIdx.x;
    int lq = tid & 15;
    int hh = tid >> 4;
#pragma unroll
    for (int r = 0; r < 4; r++) {
        int h = hh + r * 16;
        int hg = ht + h;
        int64_t base = ((int64_t)b * HD + hg) * LD + lt + lq * 4;
        float4 v = *(const float4*)(u + base);
        float d = Dv[hg];
        v.x *= d; v.y *= d; v.z *= d; v.w *= d;
        if (nt != 0) {                           // generic sparse-conv path
            int ncl = min(nt, TAP_CAP);
            float acc[4] = {v.x, v.y, v.z, v.w};
            const float* ub = u + ((int64_t)b * HD + hg) * LD;
            for (int j = 0; j < ncl; j++) {
                int hd = taps[j].hd;
                if ((hd >> 13) != hg) continue;
                int dly = hd & (KLEN - 1);
#pragma unroll
                for (int e = 0; e < 4; e++) {
                    int t = lt + lq * 4 + e;
                    int s = t - dly;
                    if (s < 0) s += KLEN;
                    if (s < LD) acc[e] += taps[j].v * ub[s];
                }
            }
            v.x = acc[0]; v.y = acc[1]; v.z = acc[2]; v.w = acc[3];
        }
        int p = h * 65 + lq * 4;
        T[p]     = silu_f(v.x);
        T[p + 1] = silu_f(v.y);
        T[p + 2] = silu_f(v.z);
        T[p + 3] = silu_f(v.w);
    }
    __syncthreads();
    int h8 = (tid & 7) * 8;
    int nb = tid >> 3;
#pragma unroll
    for (int p = 0; p < 2; p++) {
        int nl = nb + p * 32;
        short8x o;
#pragma unroll
        for (int j = 0; j < 8; j++) o[j] = (short)f2bf(T[(h8 + j) * 65 + nl]);
        int64_t n = (int64_t)b * LD + lt + nl;
        *(short8x*)(Vt + n * HD + ht + h8) = o;
    }
}

// ---------------- GEMM + GLU epilogue, BK=64 --------------------------------
// Z = Wbf(2048x1024) * Vt^T(1024x16384); out[b,h,l] = (z_a+b_a)*sigmoid(z_g+b_g)
// Block: 128 a-rows + 128 g-rows x 128 cols. BK=64 -> 16 barrier iters (vs 32):
// halves the vmcnt(0)+s_barrier drains that bound the m97-style structure.
// LDS 48KB: A(256 rows x 64k) 32KB + B(128 x 64k) 16KB. 8-slot XOR source
// swizzle keeps ds_read_b128 bank spread equal to the BK=32 layout.
__global__ __launch_bounds__(256, 2) void k_gemm(const unsigned short* __restrict__ Wbf,
                                                 const unsigned short* __restrict__ Vt,
                                                 const float* __restrict__ bvec,
                                                 float* __restrict__ out) {
    __shared__ unsigned short smem[24576];       // A: [0,16384) shorts, B: [16384,24576)
    int m0 = blockIdx.x * 128;                   // 0..896 (m fast-varying: round-1 winner)
    int n0 = blockIdx.y * 128;
    int tid = threadIdx.x;

    // staging: 3072 chunks of 16B, 12/thread; LDS dest = chunk*16B (lane-contig).
    // LDS slot s of row r holds global k-chunk (s ^ (r&7)).
    const unsigned short* gsrc[12];
    unsigned short* ldst[12];
#pragma unroll
    for (int i = 0; i < 12; i++) {
        int c = tid + i * 256;
        ldst[i] = smem + c * 8;
        if (c < 2048) {
            int r = c >> 3, s = c & 7;
            int kg = s ^ (r & 7);
            int grow = (r < 128) ? (m0 + r) : (1024 + m0 + (r - 128));
            gsrc[i] = Wbf + (int64_t)grow * HD + kg * 8;
        } else {
            int cc = c - 2048;
            int col = cc >> 3, s = cc & 7;
            int kg = s ^ (col & 7);
            gsrc[i] = Vt + (int64_t)(n0 + col) * HD + kg * 8;
        }
    }

    int lane = tid & 63;
    int wid  = tid >> 6;
    int wm = wid >> 1, wn = wid & 1;
    int l15 = lane & 15, quad = lane >> 4;
    int xr = l15 & 7;                            // row&7 for all frag rows

    int rba[4], rbg[4], rbb[4];                  // row bases (shorts)
#pragma unroll
    for (int i = 0; i < 4; i++) {
        int ra = wm * 64 + i * 16 + l15;
        rba[i] = ra * 64;
        rbg[i] = (128 + ra) * 64;
        int cb = wn * 64 + i * 16 + l15;
        rbb[i] = 16384 + cb * 64;
    }

    float4x acca[4][4], accg[4][4];
#pragma unroll
    for (int i = 0; i < 4; i++)
#pragma unroll
        for (int j = 0; j < 4; j++) {
            acca[i][j] = (float4x){0.f, 0.f, 0.f, 0.f};
            accg[i][j] = (float4x){0.f, 0.f, 0.f, 0.f};
        }

    for (int kt = 0; kt < 16; kt++) {
#pragma unroll
        for (int i = 0; i < 12; i++) gload16(gsrc[i], ldst[i]);
#pragma unroll
        for (int i = 0; i < 12; i++) gsrc[i] += 64;    // advance K by 64 bf16
        __syncthreads();
#pragma unroll
        for (int ks = 0; ks < 2; ks++) {
            int off = ((ks * 4 + quad) ^ xr) * 8;      // swizzled slot -> shorts
            short8x af[4], gf[4], bf[4];
#pragma unroll
            for (int i = 0; i < 4; i++) {
                af[i] = *(const short8x*)(smem + rba[i] + off);
                gf[i] = *(const short8x*)(smem + rbg[i] + off);
                bf[i] = *(const short8x*)(smem + rbb[i] + off);
            }
#pragma unroll
            for (int i = 0; i < 4; i++)
#pragma unroll
                for (int j = 0; j < 4; j++) {
                    acca[i][j] = __builtin_amdgcn_mfma_f32_16x16x32_bf16(af[i], bf[j], acca[i][j], 0, 0, 0);
                    accg[i][j] = __builtin_amdgcn_mfma_f32_16x16x32_bf16(gf[i], bf[j], accg[i][j], 0, 0, 0);
                }
        }
        __syncthreads();
    }

    // epilogue: out[b,h,l] = (a + b_a) * sigmoid(g + b_g)
    int b = n0 >> 12;
#pragma unroll
    for (int i = 0; i < 4; i++) {
        int h = m0 + wm * 64 + i * 16 + quad * 4;
        float ba[4], bg[4];
#pragma unroll
        for (int r = 0; r < 4; r++) { ba[r] = bvec[h + r]; bg[r] = bvec[1024 + h + r]; }
#pragma unroll
        for (int j = 0; j < 4; j++) {
            int n = n0 + wn * 64 + j * 16 + l15;
            int l = n & (LD - 1);
            float* op = out + ((int64_t)b * HD + h) * LD + l;
#pragma unroll
            for (int r = 0; r < 4; r++) {
                float av = acca[i][j][r] + ba[r];
                float gv = accg[i][j][r] + bg[r];
                op[(int64_t)r * LD] = av / (1.0f + __expf(-gv));
            }
        }
    }
}

extern "C" void kernel_launch(void* const* d_in, const int* in_sizes, int n_in,
                              void* d_out, int out_size, void* d_ws, size_t ws_size,
                              hipStream_t stream) {
    const float* u    = (const float*)d_in[0];   // (4,1024,4096)
    const float* kern = (const float*)d_in[1];   // (1,1024,8192)
    const float* Dv   = (const float*)d_in[2];   // (1,1024)
    const float* W    = (const float*)d_in[3];   // (2048,1024)
    const float* bv   = (const float*)d_in[4];   // (2048,)
    float* out = (float*)d_out;                  // (4,1024,4096)

    char* ws = (char*)d_ws;
    int* ntaps = (int*)ws;                                   // [0,256)
    Tap* taps  = (Tap*)(ws + 256);                           // 512 KiB cap
    unsigned short* Wbf = (unsigned short*)(ws + (1 << 20)); // 4 MiB
    unsigned short* Vt  = (unsigned short*)(ws + (8 << 20)); // 32 MiB

    hipMemsetAsync(ntaps, 0, 256, stream);
    hipLaunchKernelGGL(k_prep, dim3(3072),      dim3(256), 0, stream, kern, ntaps, taps, W, Wbf);
    hipLaunchKernelGGL(k_vt,   dim3(64, 16, 4), dim3(256), 0, stream, u, Dv, ntaps, taps, Vt);
    hipLaunchKernelGGL(k_gemm, dim3(8, 128),    dim3(256), 0, stream, Wbf, Vt, bv, out);
}